// Round 1
// baseline (55.866 us; speedup 1.0000x reference)
//
#include <hip/hip_runtime.h>
#include <math.h>

#define EPSF 1e-7f

constexpr int B = 16, M = 128, N = 25200, C = 80;
constexpr int THREADS = 256;
constexpr int NBLK_X = (N + THREADS - 1) / THREADS; // 99

__device__ __forceinline__ double wave_sum(double v) {
#pragma unroll
    for (int off = 32; off > 0; off >>= 1) v += __shfl_down(v, off, 64);
    return v;
}

__global__ __launch_bounds__(256) void detect_main(
    const float* __restrict__ label_box, const float* __restrict__ box,
    const float* __restrict__ prb, const float* __restrict__ cls,
    const int* __restrict__ label_cls, double* __restrict__ partial)
{
    __shared__ float4 s_lb[M];
    __shared__ float  s_area[M];
    __shared__ int    s_cls[M];

    const int b = blockIdx.y;
    const int t = threadIdx.x;

    if (t < M) {
        float4 a = reinterpret_cast<const float4*>(label_box)[b * M + t];
        s_lb[t]   = a;
        s_area[t] = fmaxf(a.z - a.x, 0.0f) * fmaxf(a.w - a.y, 0.0f);
        s_cls[t]  = label_cls[b * M + t];
    }
    __syncthreads();

    const int n = blockIdx.x * THREADS + t;

    double v_pos = 0.0, v_neg = 0.0, v_ciou = 0.0;
    double v_logp = 0.0, v_log1mp = 0.0, v_nll = 0.0;

    if (n < N) {
        const float4 bx = reinterpret_cast<const float4*>(box)[b * N + n];
        const float w2 = fmaxf(bx.z - bx.x, 0.0f);
        const float h2 = fmaxf(bx.w - bx.y, 0.0f);
        const float area_b = w2 * h2;

        float best = -1.0f;
        int   bidx = 0;
#pragma unroll 4
        for (int m = 0; m < M; ++m) {
            float4 a = s_lb[m];
            float ix1 = fmaxf(a.x, bx.x);
            float iy1 = fmaxf(a.y, bx.y);
            float ix2 = fminf(a.z, bx.z);
            float iy2 = fminf(a.w, bx.w);
            float inter = fmaxf(ix2 - ix1, 0.0f) * fmaxf(iy2 - iy1, 0.0f);
            float uni = s_area[m] + area_b - inter;
            float iou = inter / (uni + EPSF);   // masked rows give exactly 0, mask multiply is a no-op
            if (iou > best) { best = iou; bidx = m; }  // strict > == first-occurrence argmax
        }

        const bool pos = best > 0.7f;
        const bool neg = (best > 0.0f) && (best < 0.3f);

        const float p = fminf(fmaxf(prb[b * N + n], EPSF), 1.0f - EPSF);

        if (pos) {
            v_pos  = 1.0;
            v_logp = (double)(-logf(p));

            // CIoU(detect_box, box)
            float4 a = s_lb[bidx];
            float ix1 = fmaxf(a.x, bx.x);
            float iy1 = fmaxf(a.y, bx.y);
            float ix2 = fminf(a.z, bx.z);
            float iy2 = fminf(a.w, bx.w);
            float inter = fmaxf(ix2 - ix1, 0.0f) * fmaxf(iy2 - iy1, 0.0f);
            float w1 = fmaxf(a.z - a.x, 0.0f);
            float h1 = fmaxf(a.w - a.y, 0.0f);
            float uni = w1 * h1 + w2 * h2 - inter;
            float iou = inter / (uni + EPSF);
            float cw = fmaxf(a.z, bx.z) - fminf(a.x, bx.x);
            float ch = fmaxf(a.w, bx.w) - fminf(a.y, bx.y);
            float c2 = cw * cw + ch * ch + EPSF;
            float dx = (a.x + a.z - bx.x - bx.z) * 0.5f;
            float dy = (a.y + a.w - bx.y - bx.w) * 0.5f;
            float rho2 = dx * dx + dy * dy;
            float dat = atanf(w1 / (h1 + EPSF)) - atanf(w2 / (h2 + EPSF));
            float v = 0.40528473456935109f * dat * dat; // 4/pi^2
            float alpha = v / (1.0f - iou + v + EPSF);
            float ciou = iou - rho2 / c2 - alpha * v;
            v_ciou = (double)(1.0f - ciou);

            // cls NLL (sparse gather: only pos elements touch cls)
            float pc = cls[(size_t)(b * N + n) * C + s_cls[bidx]];
            pc = fminf(fmaxf(pc, EPSF), 1.0f);
            v_nll = (double)(-logf(pc));
        } else if (neg) {
            v_neg    = 1.0;
            v_log1mp = (double)(-logf(1.0f - p));
        }
    }

    // deterministic block reduction (double): wave shuffle -> LDS -> thread 0
    __shared__ double s_red[6][4];
    const int lane = t & 63;
    const int wid  = t >> 6;

    double vals[6] = { v_pos, v_neg, v_ciou, v_logp, v_log1mp, v_nll };
#pragma unroll
    for (int k = 0; k < 6; ++k) {
        double v = wave_sum(vals[k]);
        if (lane == 0) s_red[k][wid] = v;
    }
    __syncthreads();

    if (t == 0) {
        const int bid = blockIdx.y * gridDim.x + blockIdx.x;
#pragma unroll
        for (int k = 0; k < 6; ++k)
            partial[(size_t)bid * 6 + k] =
                s_red[k][0] + s_red[k][1] + s_red[k][2] + s_red[k][3];
    }
}

__global__ __launch_bounds__(256) void detect_finalize(
    const double* __restrict__ partial, int nblocks, float* __restrict__ out)
{
    double acc[6] = {0.0, 0.0, 0.0, 0.0, 0.0, 0.0};
    for (int i = threadIdx.x; i < nblocks; i += 256) {
#pragma unroll
        for (int k = 0; k < 6; ++k) acc[k] += partial[(size_t)i * 6 + k];
    }

    __shared__ double s_red[6][4];
    const int lane = threadIdx.x & 63;
    const int wid  = threadIdx.x >> 6;
#pragma unroll
    for (int k = 0; k < 6; ++k) {
        double v = wave_sum(acc[k]);
        if (lane == 0) s_red[k][wid] = v;
    }
    __syncthreads();

    if (threadIdx.x == 0) {
        double tot[6];
#pragma unroll
        for (int k = 0; k < 6; ++k)
            tot[k] = s_red[k][0] + s_red[k][1] + s_red[k][2] + s_red[k][3];

        const double npos = fmax(tot[0], 1.0);
        const double nneg = fmax(tot[1], 1.0);
        out[0] = (float)(tot[2] / npos);                     // box_loss
        out[1] = (float)(tot[3] / npos + tot[4] / nneg);     // prb_loss
        out[2] = (float)(tot[5] / npos);                     // cls_loss
    }
}

extern "C" void kernel_launch(void* const* d_in, const int* in_sizes, int n_in,
                              void* d_out, int out_size, void* d_ws, size_t ws_size,
                              hipStream_t stream) {
    const float* label_box = (const float*)d_in[0];
    const float* box       = (const float*)d_in[1];
    const float* prb       = (const float*)d_in[2];
    const float* cls       = (const float*)d_in[3];
    const int*   label_cls = (const int*)d_in[4];
    float*  out     = (float*)d_out;
    double* partial = (double*)d_ws; // NBLK_X*B*6 doubles = 76 KB

    dim3 grid(NBLK_X, B);
    detect_main<<<grid, THREADS, 0, stream>>>(label_box, box, prb, cls, label_cls, partial);
    detect_finalize<<<1, 256, 0, stream>>>(partial, NBLK_X * B, out);
}

// Round 2
// 31.830 us; speedup vs baseline: 1.7551x; 1.7551x over previous
//
#include <hip/hip_runtime.h>
#include <math.h>

#define EPSF 1e-7f

constexpr int B = 16, M = 128, N = 25200, C = 80;
constexpr int THREADS = 256;
constexpr int KN = 2;                       // n's per thread
constexpr int NPB = THREADS * KN;           // 512 n's per block
constexpr int NBLK_X = (N + NPB - 1) / NPB; // 50

__device__ __forceinline__ double wave_sum(double v) {
#pragma unroll
    for (int off = 32; off > 0; off >>= 1) v += __shfl_down(v, off, 64);
    return v;
}

__global__ __launch_bounds__(256) void detect_main(
    const float* __restrict__ label_box, const float* __restrict__ box,
    const float* __restrict__ prb, const float* __restrict__ cls,
    const int* __restrict__ label_cls, double* __restrict__ partial)
{
    __shared__ float4 s_lb[M];    // compacted valid label boxes (original order)
    __shared__ float  s_area[M];  // their areas
    __shared__ int    s_idx[M];   // compact -> original m
    __shared__ int    s_cls[M];   // full label_cls
    __shared__ int    s_cnt[4];
    __shared__ int    s_mcount;

    const int b = blockIdx.y;
    const int t = threadIdx.x;
    const int lane = t & 63;
    const int wid  = t >> 6;

    // ---- stage + order-preserving compaction of valid (any-nonzero) boxes ----
    float4 a4 = make_float4(0.f, 0.f, 0.f, 0.f);
    bool valid = false;
    if (t < M) {
        a4 = reinterpret_cast<const float4*>(label_box)[b * M + t];
        valid = (a4.x != 0.f) | (a4.y != 0.f) | (a4.z != 0.f) | (a4.w != 0.f);
        s_cls[t] = label_cls[b * M + t];
    }
    unsigned long long ball = __ballot(valid);
    if (lane == 0) s_cnt[wid] = __popcll(ball);
    __syncthreads();
    if (valid) {
        int base = 0;
#pragma unroll
        for (int w = 0; w < 4; ++w) if (w < wid) base += s_cnt[w];
        int c = base + __popcll(ball & ((1ull << lane) - 1ull));
        s_lb[c]   = a4;
        s_area[c] = fmaxf(a4.z - a4.x, 0.0f) * fmaxf(a4.w - a4.y, 0.0f);
        s_idx[c]  = t;
    }
    if (t == 0) s_mcount = s_cnt[0] + s_cnt[1] + s_cnt[2] + s_cnt[3];
    __syncthreads();
    const int mc = s_mcount;

    // ---- per-thread n state ----
    const int nbase = blockIdx.x * NPB + t;
    float4 bx[KN];
    float  areab[KN];
    bool   act[KN];
    float  ibest[KN], ubest[KN];
    int    bc[KN];
#pragma unroll
    for (int k = 0; k < KN; ++k) {
        const int n = nbase + k * THREADS;
        act[k] = (n < N);
        bx[k] = act[k] ? reinterpret_cast<const float4*>(box)[b * N + n]
                       : make_float4(0.f, 0.f, 0.f, 0.f);
        float w2 = fmaxf(bx[k].z - bx[k].x, 0.0f);
        float h2 = fmaxf(bx[k].w - bx[k].y, 0.0f);
        areab[k] = w2 * h2;
        ibest[k] = 0.0f;  // inter of best
        ubest[k] = 1.0f;  // uni+eps of best (any positive; best iou = 0/1 = 0)
        bc[k]    = 0;
    }

    // ---- division-free argmax over compacted valid boxes ----
    for (int m = 0; m < mc; ++m) {
        const float4 a  = s_lb[m];
        const float  aa = s_area[m];
#pragma unroll
        for (int k = 0; k < KN; ++k) {
            float ix1 = fmaxf(a.x, bx[k].x);
            float iy1 = fmaxf(a.y, bx[k].y);
            float ix2 = fminf(a.z, bx[k].z);
            float iy2 = fminf(a.w, bx[k].w);
            float inter = fmaxf(ix2 - ix1, 0.0f) * fmaxf(iy2 - iy1, 0.0f);
            // match reference rounding order: ((area_a+area_b)-inter)+eps
            float uni_e = ((aa + areab[k]) - inter) + EPSF;
            // inter/uni_e > ibest/ubest  <=>  inter*ubest > ibest*uni_e  (all >= 0)
            if (inter * ubest[k] > ibest[k] * uni_e) {
                ibest[k] = inter; ubest[k] = uni_e; bc[k] = m;
            }
        }
    }

    // ---- epilogue: losses ----
    double v_pos = 0.0, v_neg = 0.0, v_ciou = 0.0;
    double v_logp = 0.0, v_log1mp = 0.0, v_nll = 0.0;

#pragma unroll
    for (int k = 0; k < KN; ++k) {
        if (!act[k]) continue;
        const int n = nbase + k * THREADS;
        const float best = ibest[k] / ubest[k];   // exact divide, matches ref expr
        const bool pos = best > 0.7f;
        const bool neg = (best > 0.0f) && (best < 0.3f);
        if (!(pos | neg)) continue;

        const float p = fminf(fmaxf(prb[b * N + n], EPSF), 1.0f - EPSF);

        if (pos) {
            v_pos += 1.0;
            v_logp += (double)(-logf(p));

            float4 a = s_lb[bc[k]];
            float ix1 = fmaxf(a.x, bx[k].x);
            float iy1 = fmaxf(a.y, bx[k].y);
            float ix2 = fminf(a.z, bx[k].z);
            float iy2 = fminf(a.w, bx[k].w);
            float inter = fmaxf(ix2 - ix1, 0.0f) * fmaxf(iy2 - iy1, 0.0f);
            float w1 = fmaxf(a.z - a.x, 0.0f);
            float h1 = fmaxf(a.w - a.y, 0.0f);
            float w2 = fmaxf(bx[k].z - bx[k].x, 0.0f);
            float h2 = fmaxf(bx[k].w - bx[k].y, 0.0f);
            float uni = w1 * h1 + w2 * h2 - inter;
            float iou = inter / (uni + EPSF);
            float cw = fmaxf(a.z, bx[k].z) - fminf(a.x, bx[k].x);
            float ch = fmaxf(a.w, bx[k].w) - fminf(a.y, bx[k].y);
            float c2 = cw * cw + ch * ch + EPSF;
            float dx = (a.x + a.z - bx[k].x - bx[k].z) * 0.5f;
            float dy = (a.y + a.w - bx[k].y - bx[k].w) * 0.5f;
            float rho2 = dx * dx + dy * dy;
            float dat = atanf(w1 / (h1 + EPSF)) - atanf(w2 / (h2 + EPSF));
            float v = 0.40528473456935109f * dat * dat; // 4/pi^2
            float alpha = v / (1.0f - iou + v + EPSF);
            float ciou = iou - rho2 / c2 - alpha * v;
            v_ciou += (double)(1.0f - ciou);

            int dcls = s_cls[s_idx[bc[k]]];
            float pc = cls[(size_t)(b * N + n) * C + dcls];
            pc = fminf(fmaxf(pc, EPSF), 1.0f);
            v_nll += (double)(-logf(pc));
        } else { // neg
            v_neg += 1.0;
            v_log1mp += (double)(-logf(1.0f - p));
        }
    }

    // ---- deterministic block reduction (double) ----
    __shared__ double s_red[6][4];
    double vals[6] = { v_pos, v_neg, v_ciou, v_logp, v_log1mp, v_nll };
#pragma unroll
    for (int kk = 0; kk < 6; ++kk) {
        double v = wave_sum(vals[kk]);
        if (lane == 0) s_red[kk][wid] = v;
    }
    __syncthreads();

    if (t == 0) {
        const int bid = blockIdx.y * gridDim.x + blockIdx.x;
#pragma unroll
        for (int kk = 0; kk < 6; ++kk)
            partial[(size_t)bid * 6 + kk] =
                s_red[kk][0] + s_red[kk][1] + s_red[kk][2] + s_red[kk][3];
    }
}

__global__ __launch_bounds__(256) void detect_finalize(
    const double* __restrict__ partial, int nblocks, float* __restrict__ out)
{
    double acc[6] = {0.0, 0.0, 0.0, 0.0, 0.0, 0.0};
    for (int i = threadIdx.x; i < nblocks; i += 256) {
#pragma unroll
        for (int k = 0; k < 6; ++k) acc[k] += partial[(size_t)i * 6 + k];
    }

    __shared__ double s_red[6][4];
    const int lane = threadIdx.x & 63;
    const int wid  = threadIdx.x >> 6;
#pragma unroll
    for (int k = 0; k < 6; ++k) {
        double v = wave_sum(acc[k]);
        if (lane == 0) s_red[k][wid] = v;
    }
    __syncthreads();

    if (threadIdx.x == 0) {
        double tot[6];
#pragma unroll
        for (int k = 0; k < 6; ++k)
            tot[k] = s_red[k][0] + s_red[k][1] + s_red[k][2] + s_red[k][3];

        const double npos = fmax(tot[0], 1.0);
        const double nneg = fmax(tot[1], 1.0);
        out[0] = (float)(tot[2] / npos);                 // box_loss
        out[1] = (float)(tot[3] / npos + tot[4] / nneg); // prb_loss
        out[2] = (float)(tot[5] / npos);                 // cls_loss
    }
}

extern "C" void kernel_launch(void* const* d_in, const int* in_sizes, int n_in,
                              void* d_out, int out_size, void* d_ws, size_t ws_size,
                              hipStream_t stream) {
    const float* label_box = (const float*)d_in[0];
    const float* box       = (const float*)d_in[1];
    const float* prb       = (const float*)d_in[2];
    const float* cls       = (const float*)d_in[3];
    const int*   label_cls = (const int*)d_in[4];
    float*  out     = (float*)d_out;
    double* partial = (double*)d_ws; // NBLK_X*B*6 doubles = 38.4 KB

    dim3 grid(NBLK_X, B);
    detect_main<<<grid, THREADS, 0, stream>>>(label_box, box, prb, cls, label_cls, partial);
    detect_finalize<<<1, 256, 0, stream>>>(partial, NBLK_X * B, out);
}